// Round 16
// baseline (370.281 us; speedup 1.0000x reference)
//
#include <hip/hip_runtime.h>
#include <math.h>

typedef unsigned short u16;
typedef unsigned int u32;
typedef __attribute__((ext_vector_type(8))) __bf16 bf16x8;
typedef __attribute__((ext_vector_type(4))) float f32x4;

#define B_ 2
#define N_ 4096
#define DIM_ 1024
#define QK_ 128
#define HID_ 2048
#define M_TOT (B_*N_)   // 8192

__device__ __forceinline__ u16 f2bf(float f) {
  union { float f; u32 u; } v; v.f = f;
  u32 r = v.u + 0x7fffu + ((v.u >> 16) & 1u);
  return (u16)(r >> 16);
}
__device__ __forceinline__ float bf2f(u16 h) {
  union { u32 u; float f; } v; v.u = ((u32)h) << 16;
  return v.f;
}
// __expf -> single v_exp_f32; bf16 output absorbs the ulp loss
__device__ __forceinline__ float silu_f(float v) { return v / (1.0f + __expf(-v)); }

#define WAIT_VM(n)  asm volatile("s_waitcnt vmcnt(" #n ")" ::: "memory")
#define WAIT_LG0()  asm volatile("s_waitcnt lgkmcnt(0)" ::: "memory")

// ---------------- LayerNorm: x (f32 [8192][1024]) -> normed bf16 ----------------
__global__ __launch_bounds__(256) void ln_kernel(
    const float* __restrict__ x, const float* __restrict__ g,
    const float* __restrict__ b, u16* __restrict__ out) {
  const int row = blockIdx.x;
  const int t = threadIdx.x;
  const float4* xr = (const float4*)(x + (size_t)row * DIM_);
  float4 v = xr[t];
  float s  = v.x + v.y + v.z + v.w;
  float s2 = v.x*v.x + v.y*v.y + v.z*v.z + v.w*v.w;
  #pragma unroll
  for (int o = 32; o > 0; o >>= 1) { s += __shfl_down(s, o); s2 += __shfl_down(s2, o); }
  __shared__ float red[2][4];
  const int wave = t >> 6, lane = t & 63;
  if (lane == 0) { red[0][wave] = s; red[1][wave] = s2; }
  __syncthreads();
  float ts  = red[0][0] + red[0][1] + red[0][2] + red[0][3];
  float ts2 = red[1][0] + red[1][1] + red[1][2] + red[1][3];
  float mu  = ts * (1.0f/(float)DIM_);
  float var = ts2 * (1.0f/(float)DIM_) - mu*mu;
  float rs  = rsqrtf(var + 1e-5f);
  const float4 gg = ((const float4*)g)[t];
  const float4 bb = ((const float4*)b)[t];
  ushort4 w;
  w.x = f2bf((v.x-mu)*rs*gg.x + bb.x);
  w.y = f2bf((v.y-mu)*rs*gg.y + bb.y);
  w.z = f2bf((v.z-mu)*rs*gg.z + bb.z);
  w.w = f2bf((v.w-mu)*rs*gg.w + bb.w);
  ((ushort4*)(out + (size_t)row*DIM_))[t] = w;
}

// ---- fused transpose: all 3 weight matrices in one launch (f32 [R][C] -> bf16 [C][R]) ----
__global__ __launch_bounds__(256) void transpose_all(
    const float* __restrict__ Wh, const float* __restrict__ Wqk,
    const float* __restrict__ Wo,
    u16* __restrict__ WhT, u16* __restrict__ WqkT, u16* __restrict__ WoT) {
  int id = blockIdx.x;
  const float* in; u16* out; int R, C, cb, rb;
  if (id < 4096)      { in = Wh;  out = WhT;  R = 1024; C = 4096; cb = id & 127; rb = id >> 7; }
  else if (id < 4224) { id -= 4096; in = Wqk; out = WqkT; R = 1024; C = 128;  cb = id & 3;  rb = id >> 2; }
  else                { id -= 4224; in = Wo;  out = WoT;  R = 2048; C = 1024; cb = id & 31; rb = id >> 5; }
  __shared__ float tile[32][33];
  const int c0 = cb * 32, r0 = rb * 32;
  const int tx = threadIdx.x & 31, ty = threadIdx.x >> 5;  // 32x8
  #pragma unroll
  for (int i = 0; i < 4; ++i)
    tile[ty + i*8][tx] = in[(size_t)(r0 + ty + i*8) * C + c0 + tx];
  __syncthreads();
  #pragma unroll
  for (int i = 0; i < 4; ++i)
    out[(size_t)(c0 + ty + i*8) * R + r0 + tx] = f2bf(tile[tx][ty + i*8]);
}

enum { EPI_HV, EPI_QK, EPI_S, EPI_PV, EPI_O };

// ---- g2: 2-phase 128x128, BK=64, 256 thr, 32KB LDS, 4 blocks/CU — HV and S ----
// Both-sides swizzle: 16B chunk c of row r stored at slot c^(r&7).
// NOTE: launch_bounds MUST be (256,4): (256,5) forces VGPR<64 -> acc spills (r10).
// NOTE: do NOT fuse extra epilogue variants into EPI_HV (r11: spill, 1.76x slowdown).
template<int EPI>
__global__ __launch_bounds__(256, 4) void g2(
    const u16* __restrict__ A, int lda,
    const u16* __restrict__ BT, int ldb, int K,
    void* __restrict__ Cv, int ldc,
    const float* __restrict__ f0)
{
  int bm, bn; const int bz = blockIdx.z;
  if constexpr (EPI == EPI_HV) {
    // XCD-chunked bijective mapping (grid 32x64 = 2048 blocks, 8 XCDs)
    const int id  = (int)blockIdx.x + 32*(int)blockIdx.y;
    const int nid = (id & 7)*256 + (id >> 3);
    bm = nid & 31; bn = nid >> 5;
  } else {  // EPI_S: compact lower-triangle grid, 528 tiles per batch
    const int t = blockIdx.x;
    int r = (int)((sqrtf(8.0f*(float)t + 1.0f) - 1.0f) * 0.5f);
    if ((r+1)*(r+2)/2 <= t) ++r;
    if (r*(r+1)/2 > t) --r;
    bm = r; bn = t - r*(r+1)/2;
  }

  const u16* Ap = A; const u16* Bp = BT;
  if constexpr (EPI == EPI_S) { Ap += (size_t)bz*N_*QK_; Bp += (size_t)bz*N_*QK_; }

  __shared__ __align__(16) u16 lds[2][128*64];
  const int tid = threadIdx.x, wave = tid >> 6, lane = tid & 63;
  const int m0 = bm*128, n0 = bn*128;
  f32x4 acc[4][4] = {};
  const int wr = (wave >> 1)*64, wc = (wave & 1)*64;

  const int srow = lane >> 3;
  const int sch  = (lane & 7) ^ srow;
  const u16* ga = Ap + (size_t)(m0 + srow)*lda + sch*8;
  const u16* gb = Bp + (size_t)(n0 + srow)*ldb + sch*8;

  const int l15   = lane & 15;
  const int cswz0 = ((((lane>>4)    ) ^ (lane&7)) << 3);
  const int cswz1 = ((((lane>>4) | 4) ^ (lane&7)) << 3);

  for (int k0 = 0; k0 < K; k0 += 64) {
    #pragma unroll
    for (int t = 0; t < 4; ++t) {
      const int chunk = wave*4 + t;
      __builtin_amdgcn_global_load_lds(
          (const __attribute__((address_space(1))) void*)(ga + (size_t)(chunk*8)*lda + k0),
          (__attribute__((address_space(3))) void*)&lds[0][chunk*512], 16, 0, 0);
      __builtin_amdgcn_global_load_lds(
          (const __attribute__((address_space(1))) void*)(gb + (size_t)(chunk*8)*ldb + k0),
          (__attribute__((address_space(3))) void*)&lds[1][chunk*512], 16, 0, 0);
    }
    __syncthreads();
    #pragma unroll
    for (int kk = 0; kk < 2; ++kk) {
      const int cs = kk ? cswz1 : cswz0;
      bf16x8 af[4], bfr[4];
      #pragma unroll
      for (int i = 0; i < 4; ++i) {
        af[i]  = *(const bf16x8*)&lds[0][(wr + i*16 + l15)*64 + cs];
        bfr[i] = *(const bf16x8*)&lds[1][(wc + i*16 + l15)*64 + cs];
      }
      #pragma unroll
      for (int i = 0; i < 4; ++i)
        #pragma unroll
        for (int j = 0; j < 4; ++j)
          acc[i][j] = __builtin_amdgcn_mfma_f32_16x16x32_bf16(af[i], bfr[j], acc[i][j], 0, 0, 0);
    }
    __syncthreads();
  }

  const int er = (lane >> 4)*4;
  #pragma unroll
  for (int i = 0; i < 4; ++i) {
    #pragma unroll
    for (int j = 0; j < 4; ++j) {
      #pragma unroll
      for (int e = 0; e < 4; ++e) {
        const int row = m0 + wr + i*16 + er + e;
        const int col = n0 + wc + j*16 + l15;
        float v = acc[i][j][e];
        if constexpr (EPI == EPI_HV) {
          ((u16*)Cv)[(size_t)row*ldc + col] = f2bf(silu_f(v + f0[row]));
        } else {  // EPI_S
          float p = (row >= col && v > 0.0f) ? v*v : 0.0f;
          ((u16*)Cv)[(size_t)bz*N_*N_ + (size_t)row*ldc + col] = f2bf(p);
        }
      }
    }
  }
}

// ---------------- ring-4 4-wave kernel — QK only (corrected counted vmcnt) ----------------
template<int BM, int EPI>
__global__ __launch_bounds__(256, 2) void ring4(
    const u16* __restrict__ A, int lda,
    const u16* __restrict__ BT, int ldb, int K,
    void* __restrict__ Cv, void* __restrict__ C2v, int ldc,
    const float* __restrict__ f0, const float* __restrict__ f1,
    const float* __restrict__ f2)
{
  constexpr int FRM  = BM/32;
  constexpr int LA   = BM/64;
  constexpr int LPT  = LA + 2;        // loads per tile per thread
  constexpr int ASZ  = BM*32;
  constexpr int SLOT = ASZ + 128*32;
  __shared__ __align__(16) u16 lds[4*SLOT];

  const int bm = blockIdx.x, bn = blockIdx.y;
  const int tid = threadIdx.x, wave = tid >> 6, lane = tid & 63;
  const int wm = wave >> 1, wn = wave & 1;
  const int m0 = bm*BM, n0 = bn*128;
  const int nt = K >> 5;

  f32x4 acc[FRM][4] = {};
  const int srow = lane >> 2;
  const int sq   = (lane & 3) ^ ((srow >> 1) & 3);

  auto stage = [&](int t) {
    if (t >= nt) return;
    const int k0 = t << 5;
    u16* sA = &lds[(t & 3) * SLOT];
    u16* sB = sA + ASZ;
    #pragma unroll
    for (int c = 0; c < LA; ++c) {
      const int ch = wave*LA + c;
      const u16* src = A + (size_t)(m0 + ch*16 + srow)*lda + k0 + sq*8;
      __builtin_amdgcn_global_load_lds(
          (const __attribute__((address_space(1))) void*)src,
          (__attribute__((address_space(3))) void*)(sA + ch*512), 16, 0, 0);
    }
    #pragma unroll
    for (int c = 0; c < 2; ++c) {
      const int ch = wave*2 + c;
      const u16* src = BT + (size_t)(n0 + ch*16 + srow)*ldb + k0 + sq*8;
      __builtin_amdgcn_global_load_lds(
          (const __attribute__((address_space(1))) void*)src,
          (__attribute__((address_space(3))) void*)(sB + ch*512), 16, 0, 0);
    }
  };

  stage(0); stage(1); stage(2);

  const int l15 = lane & 15;
  const int swz = (((lane >> 4) ^ ((l15 >> 1) & 3)) << 3);
  const int rA0 = (wm*(BM/2) + l15)*32;
  const int rB0 = (wn*64 + l15)*32;

  for (int t = 0; t < nt; ++t) {
    if (t + 2 < nt)      { if constexpr (LPT==4) { WAIT_VM(8); } else { WAIT_VM(6); } }
    else if (t + 1 < nt) { if constexpr (LPT==4) { WAIT_VM(4); } else { WAIT_VM(3); } }
    else                 { WAIT_VM(0); }
    __builtin_amdgcn_s_barrier();
    stage(t + 3);

    const u16* sA = &lds[(t & 3) * SLOT];
    const u16* sB = sA + ASZ;
    bf16x8 a_[FRM], b_[4];
    #pragma unroll
    for (int j = 0; j < 4; ++j) b_[j] = *(const bf16x8*)&sB[rB0 + j*512 + swz];
    #pragma unroll
    for (int i = 0; i < FRM; ++i) a_[i] = *(const bf16x8*)&sA[rA0 + i*512 + swz];
    #pragma unroll
    for (int i = 0; i < FRM; ++i)
      #pragma unroll
      for (int j = 0; j < 4; ++j)
        acc[i][j] = __builtin_amdgcn_mfma_f32_16x16x32_bf16(a_[i], b_[j], acc[i][j], 0, 0, 0);
  }

  const int er = (lane >> 4)*4;
  #pragma unroll
  for (int fi = 0; fi < FRM; ++fi) {
    #pragma unroll
    for (int fj = 0; fj < 4; ++fj) {
      #pragma unroll
      for (int e = 0; e < 4; ++e) {
        const int row = m0 + wm*(BM/2) + fi*16 + er + e;
        const int col = n0 + wn*64 + fj*16 + l15;
        float v = acc[fi][fj][e];
        if constexpr (EPI == EPI_QK) {
          float s = silu_f(v + f0[col]);
          float q = (s*f1[col]     + f2[col])     * (1.0f/(float)N_);
          float k2 = s*f1[QK_+col] + f2[QK_+col];
          ((u16*)Cv )[(size_t)row*ldc + col] = f2bf(q);
          ((u16*)C2v)[(size_t)row*ldc + col] = f2bf(k2);
        }
      }
    }
  }
}

// ------------- p8: 8-phase pipelined GEMM, BM x BN, BK=64, 8 waves — PV/O -------------
// BN=256 (O): identical to r15. BN=512 (PV): halves P cross-XCD L2 replication
// (4 bn-blocks per P-panel instead of 8); LDS = 160KiB exactly; vmcnt ledger: LPB=4
// -> steady/prologue vmcnt(9) (= Ph2+Ph3+Ph4 stages in flight), pacing vmcnt(5).
template<int BM, int BN, int EPI>
__global__ __launch_bounds__(512, 2) void p8(
    const u16* __restrict__ A, int lda,
    const u16* __restrict__ BT, int ldb, int K,
    void* __restrict__ Cv, int ldc,
    const float* __restrict__ f0,
    const u16* __restrict__ gateT, const float* __restrict__ xres)
{
  constexpr int FR  = BM/32;
  constexpr int HF  = FR/2;
  constexpr int JF  = BN/128;        // B frags per jh-half per wave (2 / 4)
  constexpr int LPB = BN/128;        // B loads per thread per unit (2 / 4)
  constexpr int ATL = BM*64;
  constexpr int SLT = ATL + BN*64;
  constexpr int GSTR = (BN==512) ? 136 : 140;  // gate LDS stride (u16)
  __shared__ __align__(16) u16 lds[2*SLT];

  int bm, bn;
  const int bz = blockIdx.z;
  if constexpr (EPI == EPI_PV) {  // balanced: x=bn, y=bm, LPT reversal on y
    bn = blockIdx.x;
    bm = bz ? ((int)gridDim.y - 1 - (int)blockIdx.y) : (int)blockIdx.y;
  } else { bm = blockIdx.x; bn = blockIdx.y; }

  const int tid = threadIdx.x, wave = tid >> 6, lane = tid & 63;
  const int wm = wave >> 2, wn = wave & 3;
  const int m0 = bm*BM, n0 = bn*BN;
  const u16* Ap = A; const u16* Bp = BT;
  if constexpr (EPI == EPI_PV) { Ap += (size_t)bz*N_*N_; Bp += (size_t)bz*N_; }
  int kmax = K;
  if constexpr (EPI == EPI_PV) kmax = (bm+1)*BM;
  const int nt = kmax >> 6;

  const int l15  = lane & 15;
  const int c0   = (((lane>>4)    ) ^ (lane&7)) << 3;
  const int c1   = (((lane>>4) | 4) ^ (lane&7)) << 3;
  const int srow = lane >> 3;
  const int scol = ((lane&7) ^ (lane>>3)) << 3;

  f32x4 acc[FR][BN/64] = {};
  bf16x8 af[HF][2], b0[JF][2], b1[JF][2];

  auto stage = [&](int slot, int unit, int t) {
    if (t >= nt) return;
    const int k0 = t << 6;
    if (unit == 0 || unit == 3) {
      const int ih = (unit == 3) ? 1 : 0;
      constexpr int LA = BM/128;
      #pragma unroll
      for (int l = 0; l < LA; ++l) {
        const int pa = wave*LA + l;
        const int row0 = (pa/(BM/32))*(BM/2) + ih*(BM/4) + (pa%(BM/32))*8;
        __builtin_amdgcn_global_load_lds(
          (const __attribute__((address_space(1))) void*)(Ap + (size_t)(m0+row0+srow)*lda + k0 + scol),
          (__attribute__((address_space(3))) void*)&lds[slot*SLT + row0*64], 16, 0, 0);
      }
    } else {
      const int jh = (unit == 2) ? 1 : 0;
      #pragma unroll
      for (int l = 0; l < LPB; ++l) {
        const int pb = wave*LPB + l;
        int row0;
        if constexpr (BN == 512) row0 = (pb>>3)*128 + jh*64 + (pb&7)*8;
        else                     row0 = (pb>>2)*64  + jh*32 + (pb&3)*8;
        __builtin_amdgcn_global_load_lds(
          (const __attribute__((address_space(1))) void*)(Bp + (size_t)(n0+row0+srow)*ldb + k0 + scol),
          (__attribute__((address_space(3))) void*)&lds[slot*SLT + ATL + row0*64], 16, 0, 0);
      }
    }
  };
  auto rdA = [&](int slot, int ih) {
    #pragma unroll
    for (int i = 0; i < HF; ++i) {
      const int R = wm*(BM/2) + ih*(BM/4) + i*16 + l15;
      af[i][0] = *(const bf16x8*)&lds[slot*SLT + R*64 + c0];
      af[i][1] = *(const bf16x8*)&lds[slot*SLT + R*64 + c1];
    }
  };
  auto rdB = [&](int slot, int jh, bf16x8 (&bb)[JF][2]) {
    #pragma unroll
    for (int j = 0; j < JF; ++j) {
      const int R = wn*(BN/4) + jh*(BN/8) + j*16 + l15;
      bb[j][0] = *(const bf16x8*)&lds[slot*SLT + ATL + R*64 + c0];
      bb[j][1] = *(const bf16x8*)&lds[slot*SLT + ATL + R*64 + c1];
    }
  };
  auto mma = [&](int ih, int jh, bf16x8 (&bb)[JF][2]) {
    __builtin_amdgcn_s_setprio(1);
    #pragma unroll
    for (int i = 0; i < HF; ++i)
      #pragma unroll
      for (int j = 0; j < JF; ++j)
        #pragma unroll
        for (int kk = 0; kk < 2; ++kk)
          acc[ih*HF+i][jh*JF+j] = __builtin_amdgcn_mfma_f32_16x16x32_bf16(
              af[i][kk], bb[j][kk], acc[ih*HF+i][jh*JF+j], 0, 0, 0);
    __builtin_amdgcn_s_setprio(0);
  };

  #define BAR()     __builtin_amdgcn_s_barrier()
  #define PH_TAIL() { BAR(); WAIT_LG0(); }

  stage(0,0,0); stage(0,1,0); stage(0,2,0); stage(0,3,0);
  if constexpr (BN==512) { WAIT_VM(5); } else { WAIT_VM(3); }
  stage(1,0,1); stage(1,1,1); stage(1,2,1);
  if constexpr (BN==512) { WAIT_VM(9); } else { WAIT_VM(5); }
  BAR();

  const int iters = nt >> 1;
  for (int it = 0; it < iters; ++it) {
    const int kt = it*2;
    const bool last = (it == iters-1);
    rdA(0,0); rdB(0,0,b0); stage(1,3,kt+1);
    PH_TAIL(); mma(0,0,b0); BAR();
    rdB(0,1,b1); stage(0,0,kt+2);
    PH_TAIL(); mma(0,1,b1); BAR();
    rdA(0,1); stage(0,1,kt+2);
    PH_TAIL(); mma(1,1,b1); BAR();
    stage(0,2,kt+2);
    if (last) { WAIT_VM(0); }
    else { if constexpr (BN==512) { WAIT_VM(9); } else { WAIT_VM(5); } }
    PH_TAIL(); mma(1,0,b0); BAR();
    rdA(1,0); rdB(1,0,b0); stage(0,3,kt+2);
    PH_TAIL(); mma(0,0,b0); BAR();
    rdB(1,1,b1); stage(1,0,kt+3);
    PH_TAIL(); mma(0,1,b1); BAR();
    rdA(1,1); stage(1,1,kt+3);
    PH_TAIL(); mma(1,1,b1); BAR();
    stage(1,2,kt+3);
    if constexpr (BN==512) { WAIT_VM(9); } else { WAIT_VM(5); }
    PH_TAIL(); mma(1,0,b0); BAR();
  }

  // ---- PV: stage gate[n0..n0+BN-1][m0..m0+127] into LDS, stride GSTR u16 ----
  if constexpr (EPI == EPI_PV) {
    __syncthreads();   // all waves past final barrier; LDS now reusable
    if constexpr (BN == 512) {
      const int c = tid;                     // 1 thread per hid col
      const u16* gsrc = gateT + (size_t)(HID_ + n0 + c)*M_TOT + (size_t)bz*N_ + m0;
      u16* gdst = ((u16*)lds) + (size_t)c*GSTR;
      #pragma unroll
      for (int q = 0; q < 8; ++q)
        ((uint4*)gdst)[q] = ((const uint4*)gsrc)[q];   // 8x16B coalesced-per-col
    } else {
      const int c = tid >> 1, h = tid & 1;   // 2 threads per hid col
      const u16* gsrc = gateT + (size_t)(HID_ + n0 + c)*M_TOT + (size_t)bz*N_ + m0 + h*64;
      u16* gdst = ((u16*)lds) + (size_t)c*GSTR + h*64;
      #pragma unroll
      for (int q = 0; q < 8; ++q)
        ((uint2*)gdst)[q] = ((const uint2*)gsrc)[q];
    }
    __syncthreads();
  }

  const int er = (lane >> 4)*4;
  #pragma unroll
  for (int fi = 0; fi < FR; ++fi) {
    #pragma unroll
    for (int fj = 0; fj < BN/64; ++fj) {
      ushort4 g4;
      if constexpr (EPI == EPI_PV) {
        const int lc2  = wn*(BN/4) + fj*16 + l15;
        const int lrow = wm*(BM/2) + fi*16 + er;
        g4 = *(const ushort4*)(((const u16*)lds) + (size_t)lc2*GSTR + lrow);
      }
      #pragma unroll
      for (int e = 0; e < 4; ++e) {
        const int row = m0 + wm*(BM/2) + fi*16 + er + e;
        const int col = n0 + wn*(BN/4) + fj*16 + l15;
        float v = acc[fi][fj][e];
        if constexpr (EPI == EPI_PV) {
          const u16 gu = (e==0) ? g4.x : (e==1) ? g4.y : (e==2) ? g4.z : g4.w;
          ((u16*)Cv)[((size_t)bz*N_ + row)*ldc + col] = f2bf(v * bf2f(gu));
        } else {  // EPI_O
          ((float*)Cv)[(size_t)row*ldc + col] = v + f0[col] + xres[(size_t)row*DIM_ + col];
        }
      }
    }
  }
  #undef BAR
  #undef PH_TAIL
}

// ---------------- host ----------------
extern "C" void kernel_launch(void* const* d_in, const int* in_sizes, int n_in,
                              void* d_out, int out_size, void* d_ws, size_t ws_size,
                              hipStream_t stream) {
  const float* x    = (const float*)d_in[0];
  const float* ln_g = (const float*)d_in[1];
  const float* ln_b = (const float*)d_in[2];
  const float* Wh   = (const float*)d_in[3];
  const float* bh   = (const float*)d_in[4];
  const float* Wqk  = (const float*)d_in[5];
  const float* bqk  = (const float*)d_in[6];
  const float* gamma= (const float*)d_in[7];
  const float* beta = (const float*)d_in[8];
  const float* Wo   = (const float*)d_in[9];
  const float* bo   = (const float*)d_in[10];
  float* out = (float*)d_out;
  char* ws = (char*)d_ws;

  u16* normed = (u16*)(ws + 0);           // 8192x1024    16 MB
  u16* WhT    = (u16*)(ws + 16777216);    // 4096x1024     8 MB
  u16* WqkT   = (u16*)(ws + 25165824);    //  128x1024   256 KB
  u16* WoT    = (u16*)(ws + 25427968);    // 1024x2048     4 MB
  u16* hvT    = (u16*)(ws + 29622272);    // 4096x8192    64 MB  (rows 0..2047=v^T, 2048..4095=gate^T)
  u16* qs     = (u16*)(ws + 96731136);    // 8192x128      2 MB  (q * 1/n)
  u16* kb     = (u16*)(ws + 98828288);    // 8192x128      2 MB
  u16* P      = (u16*)(ws + 100925440);   // 2x4096x4096  64 MB
  u16* a2     = (u16*)(ws + 168034304);   // 8192x2048    32 MB

  ln_kernel<<<M_TOT, 256, 0, stream>>>(x, ln_g, ln_b, normed);
  transpose_all<<<6272, 256, 0, stream>>>(Wh, Wqk, Wo, WhT, WqkT, WoT);

  // hvT = silu(WhT @ normed^T + bh):  M=4096 (features), N=8192 (tokens), K=1024
  g2<EPI_HV><<<dim3(32, 64), 256, 0, stream>>>(WhT, 1024, normed, 1024, 1024,
      hvT, 8192, bh);
  // qk = silu(normed @ Wqk + bqk) -> q (scaled), k:  M=8192 (BM=64), N=128, K=1024
  ring4<64, EPI_QK><<<dim3(128, 1), 256, 0, stream>>>(normed, 1024, WqkT, 1024, 1024,
      qs, kb, 128, bqk, gamma, beta);
  // P = relu(q_s @ k^T)^2 causal:  compact triangular grid, 528 tiles x 2 batches
  g2<EPI_S><<<dim3(528, 1, 2), 256, 0, stream>>>(qs, 128, kb, 128, 128,
      P, 4096, nullptr);
  // a2 = (P @ V) * gate:  per batch M=4096, N=2048; BN=512 -> 4 bn-blocks/P-panel,
  // grid x=bn(4), y=bm(32), z=2 with y-reversal LPT
  p8<128, 512, EPI_PV><<<dim3(4, 32, 2), 512, 0, stream>>>(P, 4096, hvT, 8192, 4096,
      a2, 2048, nullptr, hvT, nullptr);
  // out = a2 @ Wo + bo + x:  M=8192, N=1024, K=2048; grid (64, 4) = 256 blocks
  p8<128, 256, EPI_O><<<dim3(64, 4), 512, 0, stream>>>(a2, 2048, WoT, 2048, 2048,
      out, 1024, bo, nullptr, x);
}

// Round 17
// 262.529 us; speedup vs baseline: 1.4104x; 1.4104x over previous
//
#include <hip/hip_runtime.h>
#include <math.h>

typedef unsigned short u16;
typedef unsigned int u32;
typedef __attribute__((ext_vector_type(8))) __bf16 bf16x8;
typedef __attribute__((ext_vector_type(4))) float f32x4;

#define B_ 2
#define N_ 4096
#define DIM_ 1024
#define QK_ 128
#define HID_ 2048
#define M_TOT (B_*N_)   // 8192

__device__ __forceinline__ u16 f2bf(float f) {
  union { float f; u32 u; } v; v.f = f;
  u32 r = v.u + 0x7fffu + ((v.u >> 16) & 1u);
  return (u16)(r >> 16);
}
__device__ __forceinline__ float bf2f(u16 h) {
  union { u32 u; float f; } v; v.u = ((u32)h) << 16;
  return v.f;
}
// __expf -> single v_exp_f32; bf16 output absorbs the ulp loss
__device__ __forceinline__ float silu_f(float v) { return v / (1.0f + __expf(-v)); }

#define WAIT_VM(n)  asm volatile("s_waitcnt vmcnt(" #n ")" ::: "memory")
#define WAIT_LG0()  asm volatile("s_waitcnt lgkmcnt(0)" ::: "memory")

// ---------------- LayerNorm: x (f32 [8192][1024]) -> normed bf16 ----------------
__global__ __launch_bounds__(256) void ln_kernel(
    const float* __restrict__ x, const float* __restrict__ g,
    const float* __restrict__ b, u16* __restrict__ out) {
  const int row = blockIdx.x;
  const int t = threadIdx.x;
  const float4* xr = (const float4*)(x + (size_t)row * DIM_);
  float4 v = xr[t];
  float s  = v.x + v.y + v.z + v.w;
  float s2 = v.x*v.x + v.y*v.y + v.z*v.z + v.w*v.w;
  #pragma unroll
  for (int o = 32; o > 0; o >>= 1) { s += __shfl_down(s, o); s2 += __shfl_down(s2, o); }
  __shared__ float red[2][4];
  const int wave = t >> 6, lane = t & 63;
  if (lane == 0) { red[0][wave] = s; red[1][wave] = s2; }
  __syncthreads();
  float ts  = red[0][0] + red[0][1] + red[0][2] + red[0][3];
  float ts2 = red[1][0] + red[1][1] + red[1][2] + red[1][3];
  float mu  = ts * (1.0f/(float)DIM_);
  float var = ts2 * (1.0f/(float)DIM_) - mu*mu;
  float rs  = rsqrtf(var + 1e-5f);
  const float4 gg = ((const float4*)g)[t];
  const float4 bb = ((const float4*)b)[t];
  ushort4 w;
  w.x = f2bf((v.x-mu)*rs*gg.x + bb.x);
  w.y = f2bf((v.y-mu)*rs*gg.y + bb.y);
  w.z = f2bf((v.z-mu)*rs*gg.z + bb.z);
  w.w = f2bf((v.w-mu)*rs*gg.w + bb.w);
  ((ushort4*)(out + (size_t)row*DIM_))[t] = w;
}

// ---- fused transpose: all 3 weight matrices in one launch (f32 [R][C] -> bf16 [C][R]) ----
__global__ __launch_bounds__(256) void transpose_all(
    const float* __restrict__ Wh, const float* __restrict__ Wqk,
    const float* __restrict__ Wo,
    u16* __restrict__ WhT, u16* __restrict__ WqkT, u16* __restrict__ WoT) {
  int id = blockIdx.x;
  const float* in; u16* out; int R, C, cb, rb;
  if (id < 4096)      { in = Wh;  out = WhT;  R = 1024; C = 4096; cb = id & 127; rb = id >> 7; }
  else if (id < 4224) { id -= 4096; in = Wqk; out = WqkT; R = 1024; C = 128;  cb = id & 3;  rb = id >> 2; }
  else                { id -= 4224; in = Wo;  out = WoT;  R = 2048; C = 1024; cb = id & 31; rb = id >> 5; }
  __shared__ float tile[32][33];
  const int c0 = cb * 32, r0 = rb * 32;
  const int tx = threadIdx.x & 31, ty = threadIdx.x >> 5;  // 32x8
  #pragma unroll
  for (int i = 0; i < 4; ++i)
    tile[ty + i*8][tx] = in[(size_t)(r0 + ty + i*8) * C + c0 + tx];
  __syncthreads();
  #pragma unroll
  for (int i = 0; i < 4; ++i)
    out[(size_t)(c0 + ty + i*8) * R + r0 + tx] = f2bf(tile[tx][ty + i*8]);
}

enum { EPI_HV, EPI_QK, EPI_S, EPI_PV, EPI_O };

// ---- g2: 2-phase 128x128, BK=64, 256 thr, 32KB LDS, 4 blocks/CU — HV and S ----
// Both-sides swizzle: 16B chunk c of row r stored at slot c^(r&7).
// NOTE: launch_bounds MUST be (256,4): (256,5) forces VGPR<64 -> acc spills (r10).
// NOTE: do NOT fuse extra epilogue variants into EPI_HV (r11: spill, 1.76x slowdown).
template<int EPI>
__global__ __launch_bounds__(256, 4) void g2(
    const u16* __restrict__ A, int lda,
    const u16* __restrict__ BT, int ldb, int K,
    void* __restrict__ Cv, int ldc,
    const float* __restrict__ f0)
{
  int bm, bn; const int bz = blockIdx.z;
  if constexpr (EPI == EPI_HV) {
    // XCD-chunked bijective mapping (grid 32x64 = 2048 blocks, 8 XCDs)
    const int id  = (int)blockIdx.x + 32*(int)blockIdx.y;
    const int nid = (id & 7)*256 + (id >> 3);
    bm = nid & 31; bn = nid >> 5;
  } else {  // EPI_S: compact lower-triangle grid, 528 tiles per batch
    const int t = blockIdx.x;
    int r = (int)((sqrtf(8.0f*(float)t + 1.0f) - 1.0f) * 0.5f);
    if ((r+1)*(r+2)/2 <= t) ++r;
    if (r*(r+1)/2 > t) --r;
    bm = r; bn = t - r*(r+1)/2;
  }

  const u16* Ap = A; const u16* Bp = BT;
  if constexpr (EPI == EPI_S) { Ap += (size_t)bz*N_*QK_; Bp += (size_t)bz*N_*QK_; }

  __shared__ __align__(16) u16 lds[2][128*64];
  const int tid = threadIdx.x, wave = tid >> 6, lane = tid & 63;
  const int m0 = bm*128, n0 = bn*128;
  f32x4 acc[4][4] = {};
  const int wr = (wave >> 1)*64, wc = (wave & 1)*64;

  const int srow = lane >> 3;
  const int sch  = (lane & 7) ^ srow;
  const u16* ga = Ap + (size_t)(m0 + srow)*lda + sch*8;
  const u16* gb = Bp + (size_t)(n0 + srow)*ldb + sch*8;

  const int l15   = lane & 15;
  const int cswz0 = ((((lane>>4)    ) ^ (lane&7)) << 3);
  const int cswz1 = ((((lane>>4) | 4) ^ (lane&7)) << 3);

  for (int k0 = 0; k0 < K; k0 += 64) {
    #pragma unroll
    for (int t = 0; t < 4; ++t) {
      const int chunk = wave*4 + t;
      __builtin_amdgcn_global_load_lds(
          (const __attribute__((address_space(1))) void*)(ga + (size_t)(chunk*8)*lda + k0),
          (__attribute__((address_space(3))) void*)&lds[0][chunk*512], 16, 0, 0);
      __builtin_amdgcn_global_load_lds(
          (const __attribute__((address_space(1))) void*)(gb + (size_t)(chunk*8)*ldb + k0),
          (__attribute__((address_space(3))) void*)&lds[1][chunk*512], 16, 0, 0);
    }
    __syncthreads();
    #pragma unroll
    for (int kk = 0; kk < 2; ++kk) {
      const int cs = kk ? cswz1 : cswz0;
      bf16x8 af[4], bfr[4];
      #pragma unroll
      for (int i = 0; i < 4; ++i) {
        af[i]  = *(const bf16x8*)&lds[0][(wr + i*16 + l15)*64 + cs];
        bfr[i] = *(const bf16x8*)&lds[1][(wc + i*16 + l15)*64 + cs];
      }
      #pragma unroll
      for (int i = 0; i < 4; ++i)
        #pragma unroll
        for (int j = 0; j < 4; ++j)
          acc[i][j] = __builtin_amdgcn_mfma_f32_16x16x32_bf16(af[i], bfr[j], acc[i][j], 0, 0, 0);
    }
    __syncthreads();
  }

  const int er = (lane >> 4)*4;
  #pragma unroll
  for (int i = 0; i < 4; ++i) {
    #pragma unroll
    for (int j = 0; j < 4; ++j) {
      #pragma unroll
      for (int e = 0; e < 4; ++e) {
        const int row = m0 + wr + i*16 + er + e;
        const int col = n0 + wc + j*16 + l15;
        float v = acc[i][j][e];
        if constexpr (EPI == EPI_HV) {
          ((u16*)Cv)[(size_t)row*ldc + col] = f2bf(silu_f(v + f0[row]));
        } else {  // EPI_S
          float p = (row >= col && v > 0.0f) ? v*v : 0.0f;
          ((u16*)Cv)[(size_t)bz*N_*N_ + (size_t)row*ldc + col] = f2bf(p);
        }
      }
    }
  }
}

// ---------------- ring-4 4-wave kernel — QK only (corrected counted vmcnt) ----------------
template<int BM, int EPI>
__global__ __launch_bounds__(256, 2) void ring4(
    const u16* __restrict__ A, int lda,
    const u16* __restrict__ BT, int ldb, int K,
    void* __restrict__ Cv, void* __restrict__ C2v, int ldc,
    const float* __restrict__ f0, const float* __restrict__ f1,
    const float* __restrict__ f2)
{
  constexpr int FRM  = BM/32;
  constexpr int LA   = BM/64;
  constexpr int LPT  = LA + 2;        // loads per tile per thread
  constexpr int ASZ  = BM*32;
  constexpr int SLOT = ASZ + 128*32;
  __shared__ __align__(16) u16 lds[4*SLOT];

  const int bm = blockIdx.x, bn = blockIdx.y;
  const int tid = threadIdx.x, wave = tid >> 6, lane = tid & 63;
  const int wm = wave >> 1, wn = wave & 1;
  const int m0 = bm*BM, n0 = bn*128;
  const int nt = K >> 5;

  f32x4 acc[FRM][4] = {};
  const int srow = lane >> 2;
  const int sq   = (lane & 3) ^ ((srow >> 1) & 3);

  auto stage = [&](int t) {
    if (t >= nt) return;
    const int k0 = t << 5;
    u16* sA = &lds[(t & 3) * SLOT];
    u16* sB = sA + ASZ;
    #pragma unroll
    for (int c = 0; c < LA; ++c) {
      const int ch = wave*LA + c;
      const u16* src = A + (size_t)(m0 + ch*16 + srow)*lda + k0 + sq*8;
      __builtin_amdgcn_global_load_lds(
          (const __attribute__((address_space(1))) void*)src,
          (__attribute__((address_space(3))) void*)(sA + ch*512), 16, 0, 0);
    }
    #pragma unroll
    for (int c = 0; c < 2; ++c) {
      const int ch = wave*2 + c;
      const u16* src = BT + (size_t)(n0 + ch*16 + srow)*ldb + k0 + sq*8;
      __builtin_amdgcn_global_load_lds(
          (const __attribute__((address_space(1))) void*)src,
          (__attribute__((address_space(3))) void*)(sB + ch*512), 16, 0, 0);
    }
  };

  stage(0); stage(1); stage(2);

  const int l15 = lane & 15;
  const int swz = (((lane >> 4) ^ ((l15 >> 1) & 3)) << 3);
  const int rA0 = (wm*(BM/2) + l15)*32;
  const int rB0 = (wn*64 + l15)*32;

  for (int t = 0; t < nt; ++t) {
    if (t + 2 < nt)      { if constexpr (LPT==4) { WAIT_VM(8); } else { WAIT_VM(6); } }
    else if (t + 1 < nt) { if constexpr (LPT==4) { WAIT_VM(4); } else { WAIT_VM(3); } }
    else                 { WAIT_VM(0); }
    __builtin_amdgcn_s_barrier();
    stage(t + 3);

    const u16* sA = &lds[(t & 3) * SLOT];
    const u16* sB = sA + ASZ;
    bf16x8 a_[FRM], b_[4];
    #pragma unroll
    for (int j = 0; j < 4; ++j) b_[j] = *(const bf16x8*)&sB[rB0 + j*512 + swz];
    #pragma unroll
    for (int i = 0; i < FRM; ++i) a_[i] = *(const bf16x8*)&sA[rA0 + i*512 + swz];
    #pragma unroll
    for (int i = 0; i < FRM; ++i)
      #pragma unroll
      for (int j = 0; j < 4; ++j)
        acc[i][j] = __builtin_amdgcn_mfma_f32_16x16x32_bf16(a_[i], b_[j], acc[i][j], 0, 0, 0);
  }

  const int er = (lane >> 4)*4;
  #pragma unroll
  for (int fi = 0; fi < FRM; ++fi) {
    #pragma unroll
    for (int fj = 0; fj < 4; ++fj) {
      #pragma unroll
      for (int e = 0; e < 4; ++e) {
        const int row = m0 + wm*(BM/2) + fi*16 + er + e;
        const int col = n0 + wn*64 + fj*16 + l15;
        float v = acc[fi][fj][e];
        if constexpr (EPI == EPI_QK) {
          float s = silu_f(v + f0[col]);
          float q = (s*f1[col]     + f2[col])     * (1.0f/(float)N_);
          float k2 = s*f1[QK_+col] + f2[QK_+col];
          ((u16*)Cv )[(size_t)row*ldc + col] = f2bf(q);
          ((u16*)C2v)[(size_t)row*ldc + col] = f2bf(k2);
        }
      }
    }
  }
}

// ------------- p8: 8-phase pipelined GEMM, BM x 256, BK=64, 8 waves — PV/O -------------
// PV: gate tile staged via LDS at stride 140 u16 (8B accesses, 2-way banks).
// PV grid: x=bn(8), y=bm(32), z-reversal LPT (r13/r15 best config).
// r14: x=bm broke per-wave XCD balance (-38%). r16: BN=512 halved P L2-replication
// (FETCH 175->112MB) but 2.1x slower (spill + unfilled deep pipeline) -> PV is
// engine-bound, not fetch-bound.
template<int BM, int EPI>
__global__ __launch_bounds__(512, 2) void p8(
    const u16* __restrict__ A, int lda,
    const u16* __restrict__ BT, int ldb, int K,
    void* __restrict__ Cv, int ldc,
    const float* __restrict__ f0,
    const u16* __restrict__ gateT, const float* __restrict__ xres)
{
  constexpr int FR  = BM/32;
  constexpr int HF  = FR/2;
  constexpr int ATL = BM*64;
  constexpr int SLT = ATL + 256*64;
  __shared__ __align__(16) u16 lds[2*SLT];

  int bm, bn;
  const int bz = blockIdx.z;
  if constexpr (EPI == EPI_PV) {  // balanced: x=bn, y=bm, LPT reversal on y
    bn = blockIdx.x;
    bm = bz ? ((int)gridDim.y - 1 - (int)blockIdx.y) : (int)blockIdx.y;
  } else { bm = blockIdx.x; bn = blockIdx.y; }

  const int tid = threadIdx.x, wave = tid >> 6, lane = tid & 63;
  const int wm = wave >> 2, wn = wave & 3;
  const int m0 = bm*BM, n0 = bn*256;
  const u16* Ap = A; const u16* Bp = BT;
  if constexpr (EPI == EPI_PV) { Ap += (size_t)bz*N_*N_; Bp += (size_t)bz*N_; }
  int kmax = K;
  if constexpr (EPI == EPI_PV) kmax = (bm+1)*BM;
  const int nt = kmax >> 6;

  const int l15  = lane & 15;
  const int c0   = (((lane>>4)    ) ^ (lane&7)) << 3;
  const int c1   = (((lane>>4) | 4) ^ (lane&7)) << 3;
  const int srow = lane >> 3;
  const int scol = ((lane&7) ^ (lane>>3)) << 3;

  f32x4 acc[FR][4] = {};
  bf16x8 af[HF][2], b0[2][2], b1[2][2];

  auto stage = [&](int slot, int unit, int t) {
    if (t >= nt) return;
    const int k0 = t << 6;
    if (unit == 0 || unit == 3) {
      const int ih = (unit == 3) ? 1 : 0;
      constexpr int LA = BM/128;
      #pragma unroll
      for (int l = 0; l < LA; ++l) {
        const int pa = wave*LA + l;
        const int row0 = (pa/(BM/32))*(BM/2) + ih*(BM/4) + (pa%(BM/32))*8;
        __builtin_amdgcn_global_load_lds(
          (const __attribute__((address_space(1))) void*)(Ap + (size_t)(m0+row0+srow)*lda + k0 + scol),
          (__attribute__((address_space(3))) void*)&lds[slot*SLT + row0*64], 16, 0, 0);
      }
    } else {
      const int jh = (unit == 2) ? 1 : 0;
      #pragma unroll
      for (int l = 0; l < 2; ++l) {
        const int pb = wave*2 + l;
        const int row0 = (pb>>2)*64 + jh*32 + (pb&3)*8;
        __builtin_amdgcn_global_load_lds(
          (const __attribute__((address_space(1))) void*)(Bp + (size_t)(n0+row0+srow)*ldb + k0 + scol),
          (__attribute__((address_space(3))) void*)&lds[slot*SLT + ATL + row0*64], 16, 0, 0);
      }
    }
  };
  auto rdA = [&](int slot, int ih) {
    #pragma unroll
    for (int i = 0; i < HF; ++i) {
      const int R = wm*(BM/2) + ih*(BM/4) + i*16 + l15;
      af[i][0] = *(const bf16x8*)&lds[slot*SLT + R*64 + c0];
      af[i][1] = *(const bf16x8*)&lds[slot*SLT + R*64 + c1];
    }
  };
  auto rdB = [&](int slot, int jh, bf16x8 (&bb)[2][2]) {
    #pragma unroll
    for (int j = 0; j < 2; ++j) {
      const int R = wn*64 + jh*32 + j*16 + l15;
      bb[j][0] = *(const bf16x8*)&lds[slot*SLT + ATL + R*64 + c0];
      bb[j][1] = *(const bf16x8*)&lds[slot*SLT + ATL + R*64 + c1];
    }
  };
  auto mma = [&](int ih, int jh, bf16x8 (&bb)[2][2]) {
    __builtin_amdgcn_s_setprio(1);
    #pragma unroll
    for (int i = 0; i < HF; ++i)
      #pragma unroll
      for (int j = 0; j < 2; ++j)
        #pragma unroll
        for (int kk = 0; kk < 2; ++kk)
          acc[ih*HF+i][jh*2+j] = __builtin_amdgcn_mfma_f32_16x16x32_bf16(
              af[i][kk], bb[j][kk], acc[ih*HF+i][jh*2+j], 0, 0, 0);
    __builtin_amdgcn_s_setprio(0);
  };

  #define BAR()     __builtin_amdgcn_s_barrier()
  #define PH_TAIL() { BAR(); WAIT_LG0(); }
  #define LG8()     if constexpr (BM==256) { asm volatile("s_waitcnt lgkmcnt(8)" ::: "memory"); }

  stage(0,0,0); stage(0,1,0); stage(0,2,0); stage(0,3,0);
  if constexpr (BM==256) { WAIT_VM(4); } else { WAIT_VM(3); }
  stage(1,0,1); stage(1,1,1); stage(1,2,1);
  if constexpr (BM==256) { WAIT_VM(6); } else { WAIT_VM(5); }
  BAR();

  const int iters = nt >> 1;
  for (int it = 0; it < iters; ++it) {
    const int kt = it*2;
    const bool last = (it == iters-1);
    rdA(0,0); rdB(0,0,b0); stage(1,3,kt+1);
    LG8();
    PH_TAIL(); mma(0,0,b0); BAR();
    rdB(0,1,b1); stage(0,0,kt+2);
    PH_TAIL(); mma(0,1,b1); BAR();
    rdA(0,1); stage(0,1,kt+2);
    PH_TAIL(); mma(1,1,b1); BAR();
    stage(0,2,kt+2);
    if (last) { WAIT_VM(0); }
    else if constexpr (BM==256) { WAIT_VM(6); } else { WAIT_VM(5); }
    PH_TAIL(); mma(1,0,b0); BAR();
    rdA(1,0); rdB(1,0,b0); stage(0,3,kt+2);
    LG8();
    PH_TAIL(); mma(0,0,b0); BAR();
    rdB(1,1,b1); stage(1,0,kt+3);
    PH_TAIL(); mma(0,1,b1); BAR();
    rdA(1,1); stage(1,1,kt+3);
    PH_TAIL(); mma(1,1,b1); BAR();
    stage(1,2,kt+3);
    if constexpr (BM==256) { WAIT_VM(6); } else { WAIT_VM(5); }
    PH_TAIL(); mma(1,0,b0); BAR();
  }

  // ---- PV: stage gate[n0..n0+255][m0..m0+127] into LDS, stride 140 u16 ----
  if constexpr (EPI == EPI_PV) {
    __syncthreads();   // all waves past final barrier; LDS now reusable
    {
      const int c = tid >> 1, h = tid & 1;   // c = local hid col 0..255
      const u16* gsrc = gateT + (size_t)(HID_ + n0 + c)*M_TOT + (size_t)bz*N_ + m0 + h*64;
      u16* gdst = ((u16*)lds) + (size_t)c*140 + h*64;
      #pragma unroll
      for (int q = 0; q < 8; ++q)
        ((uint2*)gdst)[q] = ((const uint2*)gsrc)[q];   // 8x8B coalesced
    }
    __syncthreads();
  }

  const int er = (lane >> 4)*4;
  #pragma unroll
  for (int fi = 0; fi < FR; ++fi) {
    #pragma unroll
    for (int fj = 0; fj < 4; ++fj) {
      ushort4 g4;
      if constexpr (EPI == EPI_PV) {
        const int lc2  = wn*64 + fj*16 + l15;
        const int lrow = wm*(BM/2) + fi*16 + er;
        g4 = *(const ushort4*)(((const u16*)lds) + (size_t)lc2*140 + lrow);
      }
      #pragma unroll
      for (int e = 0; e < 4; ++e) {
        const int row = m0 + wm*(BM/2) + fi*16 + er + e;
        const int col = n0 + wn*64 + fj*16 + l15;
        float v = acc[fi][fj][e];
        if constexpr (EPI == EPI_PV) {
          const u16 gu = (e==0) ? g4.x : (e==1) ? g4.y : (e==2) ? g4.z : g4.w;
          ((u16*)Cv)[((size_t)bz*N_ + row)*ldc + col] = f2bf(v * bf2f(gu));
        } else {  // EPI_O
          ((float*)Cv)[(size_t)row*ldc + col] = v + f0[col] + xres[(size_t)row*DIM_ + col];
        }
      }
    }
  }
  #undef BAR
  #undef PH_TAIL
  #undef LG8
}

// ---------------- host ----------------
extern "C" void kernel_launch(void* const* d_in, const int* in_sizes, int n_in,
                              void* d_out, int out_size, void* d_ws, size_t ws_size,
                              hipStream_t stream) {
  const float* x    = (const float*)d_in[0];
  const float* ln_g = (const float*)d_in[1];
  const float* ln_b = (const float*)d_in[2];
  const float* Wh   = (const float*)d_in[3];
  const float* bh   = (const float*)d_in[4];
  const float* Wqk  = (const float*)d_in[5];
  const float* bqk  = (const float*)d_in[6];
  const float* gamma= (const float*)d_in[7];
  const float* beta = (const float*)d_in[8];
  const float* Wo   = (const float*)d_in[9];
  const float* bo   = (const float*)d_in[10];
  float* out = (float*)d_out;
  char* ws = (char*)d_ws;

  u16* normed = (u16*)(ws + 0);           // 8192x1024    16 MB
  u16* WhT    = (u16*)(ws + 16777216);    // 4096x1024     8 MB
  u16* WqkT   = (u16*)(ws + 25165824);    //  128x1024   256 KB
  u16* WoT    = (u16*)(ws + 25427968);    // 1024x2048     4 MB
  u16* hvT    = (u16*)(ws + 29622272);    // 4096x8192    64 MB  (rows 0..2047=v^T, 2048..4095=gate^T)
  u16* qs     = (u16*)(ws + 96731136);    // 8192x128      2 MB  (q * 1/n)
  u16* kb     = (u16*)(ws + 98828288);    // 8192x128      2 MB
  u16* P      = (u16*)(ws + 100925440);   // 2x4096x4096  64 MB
  u16* a2     = (u16*)(ws + 168034304);   // 8192x2048    32 MB

  ln_kernel<<<M_TOT, 256, 0, stream>>>(x, ln_g, ln_b, normed);
  transpose_all<<<6272, 256, 0, stream>>>(Wh, Wqk, Wo, WhT, WqkT, WoT);

  // hvT = silu(WhT @ normed^T + bh):  M=4096 (features), N=8192 (tokens), K=1024
  g2<EPI_HV><<<dim3(32, 64), 256, 0, stream>>>(WhT, 1024, normed, 1024, 1024,
      hvT, 8192, bh);
  // qk = silu(normed @ Wqk + bqk) -> q (scaled), k:  M=8192 (BM=64), N=128, K=1024
  ring4<64, EPI_QK><<<dim3(128, 1), 256, 0, stream>>>(normed, 1024, WqkT, 1024, 1024,
      qs, kb, 128, bqk, gamma, beta);
  // P = relu(q_s @ k^T)^2 causal:  compact triangular grid, 528 tiles x 2 batches
  g2<EPI_S><<<dim3(528, 1, 2), 256, 0, stream>>>(qs, 128, kb, 128, 128,
      P, 4096, nullptr);
  // a2 = (P @ V) * gate:  per batch M=4096, N=2048; x=bn(8), y=bm(32), z=2, LPT
  p8<128, EPI_PV><<<dim3(8, 32, 2), 512, 0, stream>>>(P, 4096, hvT, 8192, 4096,
      a2, 2048, nullptr, hvT, nullptr);
  // out = a2 @ Wo + bo + x:  M=8192, N=1024, K=2048; grid (64, 4) = 256 blocks
  p8<128, EPI_O><<<dim3(64, 4), 512, 0, stream>>>(a2, 2048, WoT, 2048, 2048,
      out, 1024, bo, nullptr, x);
}